// Round 1
// baseline (52.855 us; speedup 1.0000x reference)
//
#include <hip/hip_runtime.h>

// PlayCell hysteresis scan:
//   y[t]   = kernel * x[t]
//   out[t] = min(max(out[t-1], y[t]), y[t] + W)   (play operator, W = 1.0)
// Clamp maps are closed under composition -> associative parallel scan over
// (L,H) pairs. combine(a then b): L = min(max(La,Lb),Hb), H = min(max(Ha,Lb),Hb).

#define T_LEN   16777216
#define NTH     256
#define SEG     32
#define NB      (T_LEN / (NTH * SEG))   // 2048 blocks; NB*NTH*SEG == T_LEN exactly
#define WPLAY   1.0f

__device__ __forceinline__ void combine(float La, float Ha, float Lb, float Hb,
                                        float& Lo, float& Ho) {
    // composition: apply a first, then b
    Lo = fminf(fmaxf(La, Lb), Hb);
    Ho = fminf(fmaxf(Ha, Lb), Hb);
}

// ---------------- pass 1: per-block clamp summaries ----------------
__global__ __launch_bounds__(NTH) void pass1(const float* __restrict__ x,
                                             const float* __restrict__ kptr,
                                             float* __restrict__ bsum /* NB*2 */) {
    const float k  = kptr[0];
    const int tid  = threadIdx.x;
    const int bid  = blockIdx.x;
    const int lane = tid & 63;
    const int wid  = tid >> 6;
    const long base = ((long)bid * NTH + tid) * SEG;
    const float4* xv = (const float4*)(x + base);

    float L = -INFINITY, H = INFINITY;
#pragma unroll
    for (int i = 0; i < SEG / 4; ++i) {
        float4 v = xv[i];
        float a0 = v.x, a1 = v.y, a2 = v.z, a3 = v.w;
        float y, hi;
        y = k * a0; hi = y + WPLAY; L = fminf(fmaxf(L, y), hi); H = fminf(fmaxf(H, y), hi);
        y = k * a1; hi = y + WPLAY; L = fminf(fmaxf(L, y), hi); H = fminf(fmaxf(H, y), hi);
        y = k * a2; hi = y + WPLAY; L = fminf(fmaxf(L, y), hi); H = fminf(fmaxf(H, y), hi);
        y = k * a3; hi = y + WPLAY; L = fminf(fmaxf(L, y), hi); H = fminf(fmaxf(H, y), hi);
    }

    // ordered butterfly reduce across the 64-lane wave (non-commutative op)
#pragma unroll
    for (int d = 1; d < 64; d <<= 1) {
        float Lp = __shfl_xor(L, d);
        float Hp = __shfl_xor(H, d);
        float Ln, Hn;
        if (lane & d) combine(Lp, Hp, L, H, Ln, Hn);   // partner precedes me
        else          combine(L, H, Lp, Hp, Ln, Hn);   // I precede partner
        L = Ln; H = Hn;
    }

    __shared__ float wL[NTH / 64], wH[NTH / 64];
    if (lane == 0) { wL[wid] = L; wH[wid] = H; }
    __syncthreads();
    if (tid == 0) {
        float Lt = wL[0], Ht = wH[0];
#pragma unroll
        for (int w = 1; w < NTH / 64; ++w) {
            float Ln, Hn; combine(Lt, Ht, wL[w], wH[w], Ln, Hn); Lt = Ln; Ht = Hn;
        }
        bsum[2 * bid]     = Lt;
        bsum[2 * bid + 1] = Ht;
    }
}

// ---------------- pass 2: scan block summaries -> entering state per block ----
__global__ __launch_bounds__(NTH) void pass2(const float* __restrict__ bsum,
                                             const float* __restrict__ s0ptr,
                                             float* __restrict__ sin /* NB */) {
    const int Q    = NB / NTH;  // 8 summaries per thread
    const int tid  = threadIdx.x;
    const int lane = tid & 63;
    const int wid  = tid >> 6;

    float Ls[NB / NTH], Hs[NB / NTH];
    float L = -INFINITY, H = INFINITY;
#pragma unroll
    for (int j = 0; j < Q; ++j) {
        Ls[j] = bsum[2 * (tid * Q + j)];
        Hs[j] = bsum[2 * (tid * Q + j) + 1];
        float Ln, Hn; combine(L, H, Ls[j], Hs[j], Ln, Hn); L = Ln; H = Hn;
    }

    // wave inclusive scan (Hillis-Steele, ordered)
#pragma unroll
    for (int d = 1; d < 64; d <<= 1) {
        float Lp = __shfl_up(L, d);
        float Hp = __shfl_up(H, d);
        if (lane >= d) { float Ln, Hn; combine(Lp, Hp, L, H, Ln, Hn); L = Ln; H = Hn; }
    }
    // exclusive within wave
    float eL = __shfl_up(L, 1), eH = __shfl_up(H, 1);
    if (lane == 0) { eL = -INFINITY; eH = INFINITY; }

    __shared__ float wL[NTH / 64], wH[NTH / 64];
    if (lane == 63) { wL[wid] = L; wH[wid] = H; }
    __syncthreads();

    float s = s0ptr[0];
    for (int w = 0; w < wid; ++w) s = fminf(fmaxf(s, wL[w]), wH[w]);
    s = fminf(fmaxf(s, eL), eH);

#pragma unroll
    for (int j = 0; j < Q; ++j) {
        sin[tid * Q + j] = s;
        s = fminf(fmaxf(s, Ls[j]), Hs[j]);
    }
}

// ---------------- pass 3: recompute + emit outputs ----------------
__global__ __launch_bounds__(NTH) void pass3(const float* __restrict__ x,
                                             const float* __restrict__ kptr,
                                             const float* __restrict__ sin,
                                             float* __restrict__ out) {
    const float k  = kptr[0];
    const int tid  = threadIdx.x;
    const int bid  = blockIdx.x;
    const int lane = tid & 63;
    const int wid  = tid >> 6;
    const long base = ((long)bid * NTH + tid) * SEG;
    const float4* xv = (const float4*)(x + base);

    float4 vs[SEG / 4];
#pragma unroll
    for (int i = 0; i < SEG / 4; ++i) vs[i] = xv[i];

    float L = -INFINITY, H = INFINITY;
#pragma unroll
    for (int i = 0; i < SEG / 4; ++i) {
        float a0 = vs[i].x, a1 = vs[i].y, a2 = vs[i].z, a3 = vs[i].w;
        float y, hi;
        y = k * a0; hi = y + WPLAY; L = fminf(fmaxf(L, y), hi); H = fminf(fmaxf(H, y), hi);
        y = k * a1; hi = y + WPLAY; L = fminf(fmaxf(L, y), hi); H = fminf(fmaxf(H, y), hi);
        y = k * a2; hi = y + WPLAY; L = fminf(fmaxf(L, y), hi); H = fminf(fmaxf(H, y), hi);
        y = k * a3; hi = y + WPLAY; L = fminf(fmaxf(L, y), hi); H = fminf(fmaxf(H, y), hi);
    }

    // wave inclusive scan (ordered)
#pragma unroll
    for (int d = 1; d < 64; d <<= 1) {
        float Lp = __shfl_up(L, d);
        float Hp = __shfl_up(H, d);
        if (lane >= d) { float Ln, Hn; combine(Lp, Hp, L, H, Ln, Hn); L = Ln; H = Hn; }
    }
    float eL = __shfl_up(L, 1), eH = __shfl_up(H, 1);
    if (lane == 0) { eL = -INFINITY; eH = INFINITY; }

    __shared__ float wLs[NTH / 64], wHs[NTH / 64];
    if (lane == 63) { wLs[wid] = L; wHs[wid] = H; }
    __syncthreads();

    float s = sin[bid];
    for (int w = 0; w < wid; ++w) s = fminf(fmaxf(s, wLs[w]), wHs[w]);
    s = fminf(fmaxf(s, eL), eH);

    float4* ov = (float4*)(out + base);
#pragma unroll
    for (int i = 0; i < SEG / 4; ++i) {
        float a0 = vs[i].x, a1 = vs[i].y, a2 = vs[i].z, a3 = vs[i].w;
        float4 o;
        float y;
        y = k * a0; s = fminf(fmaxf(s, y), y + WPLAY); o.x = s;
        y = k * a1; s = fminf(fmaxf(s, y), y + WPLAY); o.y = s;
        y = k * a2; s = fminf(fmaxf(s, y), y + WPLAY); o.z = s;
        y = k * a3; s = fminf(fmaxf(s, y), y + WPLAY); o.w = s;
        ov[i] = o;
    }
}

extern "C" void kernel_launch(void* const* d_in, const int* in_sizes, int n_in,
                              void* d_out, int out_size, void* d_ws, size_t ws_size,
                              hipStream_t stream) {
    const float* x  = (const float*)d_in[0];   // (T,) float32
    const float* st = (const float*)d_in[1];   // scalar initial state
    const float* kn = (const float*)d_in[2];   // scalar kernel weight
    float* out  = (float*)d_out;

    float* bsum = (float*)d_ws;        // NB*2 floats: per-block (L,H)
    float* sin  = bsum + 2 * NB;       // NB floats: entering state per block

    pass1<<<NB, NTH, 0, stream>>>(x, kn, bsum);
    pass2<<<1, NTH, 0, stream>>>(bsum, st, sin);
    pass3<<<NB, NTH, 0, stream>>>(x, kn, sin, out);
}